// Round 4
// baseline (94.993 us; speedup 1.0000x reference)
//
#include <hip/hip_runtime.h>

// Problem constants (fixed by init_kwargs)
//   key:    [B=2, N=8, T_K=8, K_H=14, K_W=14, C=64]  f32
//   scores: [B=2, N=8, 1568, 1568]                   f32
//   h_emb:  [27, 64], w_emb: [27, 64], t_emb: [15, 64]
//   out:    [B, N, 1568, 1568] f32
//
// rel_h[bn, qh, k] = dot(h_emb[kh-qh+13, :], key[bn, k, :])   k = tk*196+kh*14+kw
// rel_w[bn, qw, k] = dot(w_emb[kw-qw+13, :], key[bn, k, :])
// rel_t[bn, tq, k] = dot(t_emb[tk-tq+ 7, :], key[bn, k, :])
// out[bn, (tq,qh,qw), k] = scores + rel_h + rel_w + rel_t

typedef float f4 __attribute__((ext_vector_type(4)));

#define BN_TOTAL    16
#define KLEN        1568
#define KLEN4       392
#define QLEN        1568
#define KV_TOTAL    (BN_TOTAL * KLEN)            // 25088 key vectors
#define REL_H_ELEMS (BN_TOTAL * 14 * KLEN)       // 351232
#define REL_T_ELEMS (BN_TOTAL * 8 * KLEN)        // 200704

#define EROWS  69     // 27 h + 27 w + 15 t
#define EPITCH 68     // 64 + 4 pad floats; 272B row stride (16B aligned)

// One thread per key vector; 128-thread blocks so 196 blocks cover more CUs.
__global__ __launch_bounds__(128) void rel_fused(const float* __restrict__ key,
                                                 const float* __restrict__ hemb,
                                                 const float* __restrict__ wemb,
                                                 const float* __restrict__ temb,
                                                 float* __restrict__ relh,
                                                 float* __restrict__ relw,
                                                 float* __restrict__ relt)
{
    __shared__ float se[EROWS * EPITCH];
    for (int idx = threadIdx.x; idx < EROWS * 64; idx += 128) {
        int row = idx >> 6, c = idx & 63;
        float v;
        if (row < 27)      v = hemb[row * 64 + c];
        else if (row < 54) v = wemb[(row - 27) * 64 + c];
        else               v = temb[(row - 54) * 64 + c];
        se[row * EPITCH + c] = v;
    }
    __syncthreads();

    int kv  = blockIdx.x * 128 + threadIdx.x;   // grid exact: KV_TOTAL/128 = 196
    int bn  = kv / KLEN;
    int k   = kv - bn * KLEN;
    int tk  = k / 196;
    int khw = k - tk * 196;
    int kh  = khw / 14;
    int kw  = khw - kh * 14;

    f4 kr[16];
    const f4* kp = (const f4*)(key + (size_t)kv * 64);
#pragma unroll
    for (int c = 0; c < 16; ++c) kr[c] = kp[c];

#pragma unroll
    for (int q = 0; q < 14; ++q) {
        const f4* e = (const f4*)(se + (kh - q + 13) * EPITCH);
        float acc = 0.f;
#pragma unroll
        for (int c = 0; c < 16; ++c) {
            f4 ev = e[c];
            acc += kr[c].x * ev.x + kr[c].y * ev.y + kr[c].z * ev.z + kr[c].w * ev.w;
        }
        relh[(bn * 14 + q) * KLEN + k] = acc;
    }
#pragma unroll
    for (int q = 0; q < 14; ++q) {
        const f4* e = (const f4*)(se + (27 + kw - q + 13) * EPITCH);
        float acc = 0.f;
#pragma unroll
        for (int c = 0; c < 16; ++c) {
            f4 ev = e[c];
            acc += kr[c].x * ev.x + kr[c].y * ev.y + kr[c].z * ev.z + kr[c].w * ev.w;
        }
        relw[(bn * 14 + q) * KLEN + k] = acc;
    }
#pragma unroll
    for (int q = 0; q < 8; ++q) {
        const f4* e = (const f4*)(se + (54 + tk - q + 7) * EPITCH);
        float acc = 0.f;
#pragma unroll
        for (int c = 0; c < 16; ++c) {
            f4 ev = e[c];
            acc += kr[c].x * ev.x + kr[c].y * ev.y + kr[c].z * ev.z + kr[c].w * ev.w;
        }
        relt[(bn * 8 + q) * KLEN + k] = acc;
    }
}

// One block = 2 consecutive output rows (784 f4). All row->index division
// hoisted to block scope; element loop is pure streaming with 12-16 loads
// in flight per thread before any store.
__global__ __launch_bounds__(256) void add_rows(const f4* __restrict__ scores,
                                                const f4* __restrict__ relh,
                                                const f4* __restrict__ relw,
                                                const f4* __restrict__ relt,
                                                f4* __restrict__ out)
{
    int row0 = blockIdx.x * 2;            // composite row index bn*1568+q
    int row1 = row0 + 1;                  // same bn as row0 (1568 is even)

    int bn  = row0 / QLEN;
    int q0  = row0 - bn * QLEN;
    int q1  = q0 + 1;                     // q1 < 1568 always (row pairs aligned)

    int tq0 = q0 / 196, r0 = q0 - tq0 * 196, qh0 = r0 / 14, qw0 = r0 - qh0 * 14;
    int tq1 = q1 / 196, r1 = q1 - tq1 * 196, qh1 = r1 / 14, qw1 = r1 - qh1 * 14;

    int sbase = row0 * KLEN4;             // contiguous 784-f4 span for scores/out
    int hb0 = (bn * 14 + qh0) * KLEN4, hb1 = (bn * 14 + qh1) * KLEN4;
    int wb0 = (bn * 14 + qw0) * KLEN4, wb1 = (bn * 14 + qw1) * KLEN4;
    int tb0 = (bn *  8 + tq0) * KLEN4, tb1 = (bn *  8 + tq1) * KLEN4;

    int tid = threadIdx.x;

    f4 s[4], h[4], w[4], t[4];
    int pos[4];
#pragma unroll
    for (int j = 0; j < 4; ++j) {
        int p = tid + j * 256;            // 0..784+  (784 = 2*392)
        pos[j] = p;
        bool valid = (j < 3) | (tid < 16);
        if (valid) {
            bool second = p >= KLEN4;
            int  c4 = second ? p - KLEN4 : p;
            s[j] = scores[sbase + p];
            h[j] = relh[(second ? hb1 : hb0) + c4];
            w[j] = relw[(second ? wb1 : wb0) + c4];
            t[j] = relt[(second ? tb1 : tb0) + c4];
        }
    }
#pragma unroll
    for (int j = 0; j < 4; ++j) {
        bool valid = (j < 3) | (tid < 16);
        if (valid) out[sbase + pos[j]] = s[j] + h[j] + w[j] + t[j];
    }
}

extern "C" void kernel_launch(void* const* d_in, const int* in_sizes, int n_in,
                              void* d_out, int out_size, void* d_ws, size_t ws_size,
                              hipStream_t stream)
{
    const float* key    = (const float*)d_in[0];
    const float* scores = (const float*)d_in[1];
    const float* hemb   = (const float*)d_in[2];
    const float* wemb   = (const float*)d_in[3];
    const float* temb   = (const float*)d_in[4];
    float*       out    = (float*)d_out;

    size_t need = (size_t)(REL_H_ELEMS * 2 + REL_T_ELEMS) * sizeof(float); // ~3.45 MB
    if (ws_size < need) return;

    float* relh = (float*)d_ws;
    float* relw = relh + REL_H_ELEMS;
    float* relt = relw + REL_H_ELEMS;

    rel_fused<<<KV_TOTAL / 128, 128, 0, stream>>>(key, hemb, wemb, temb, relh, relw, relt);

    // 25088 rows total, 2 rows per block
    add_rows<<<(BN_TOTAL * QLEN) / 2, 256, 0, stream>>>((const f4*)scores,
                                                        (const f4*)relh,
                                                        (const f4*)relw,
                                                        (const f4*)relt,
                                                        (f4*)out);
}

// Round 5
// 81.740 us; speedup vs baseline: 1.1621x; 1.1621x over previous
//
#include <hip/hip_runtime.h>

// Problem constants (fixed by init_kwargs)
//   key:    [B=2, N=8, T_K=8, K_H=14, K_W=14, C=64]  f32
//   scores: [B=2, N=8, 1568, 1568]                   f32
//   h_emb:  [27, 64], w_emb: [27, 64], t_emb: [15, 64]
//   out:    [B, N, 1568, 1568] f32
//
// rel_h[bn, qh, k] = dot(h_emb[kh-qh+13, :], key[bn, k, :])   k = tk*196+kh*14+kw
// rel_w[bn, qw, k] = dot(w_emb[kw-qw+13, :], key[bn, k, :])
// rel_t[bn, tq, k] = dot(t_emb[tk-tq+ 7, :], key[bn, k, :])
// out[bn, (tq,qh,qw), k] = scores + rel_h + rel_w + rel_t

typedef float f4 __attribute__((ext_vector_type(4)));

#define BN_TOTAL    16
#define KLEN        1568
#define KLEN4       392
#define QLEN        1568
#define KV_TOTAL    (BN_TOTAL * KLEN)            // 25088 key vectors
#define REL_H_ELEMS (BN_TOTAL * 14 * KLEN)       // 351232
#define REL_T_ELEMS (BN_TOTAL * 8 * KLEN)        // 200704

#define EROWS  69     // 27 h + 27 w + 15 t
#define EPITCH 68     // 64 + 4 pad floats; 272B row stride (16B aligned)

// ---------------- stage 1: rel tables (tiny, LDS-BW bound, ~4 us) ----------
__global__ __launch_bounds__(128) void rel_fused(const float* __restrict__ key,
                                                 const float* __restrict__ hemb,
                                                 const float* __restrict__ wemb,
                                                 const float* __restrict__ temb,
                                                 float* __restrict__ relh,
                                                 float* __restrict__ relw,
                                                 float* __restrict__ relt)
{
    __shared__ float se[EROWS * EPITCH];
    for (int idx = threadIdx.x; idx < EROWS * 64; idx += 128) {
        int row = idx >> 6, c = idx & 63;
        float v;
        if (row < 27)      v = hemb[row * 64 + c];
        else if (row < 54) v = wemb[(row - 27) * 64 + c];
        else               v = temb[(row - 54) * 64 + c];
        se[row * EPITCH + c] = v;
    }
    __syncthreads();

    int kv  = blockIdx.x * 128 + threadIdx.x;   // grid exact: 196 blocks
    int bn  = kv / KLEN;
    int k   = kv - bn * KLEN;
    int tk  = k / 196;
    int khw = k - tk * 196;
    int kh  = khw / 14;
    int kw  = khw - kh * 14;

    f4 kr[16];
    const f4* kp = (const f4*)(key + (size_t)kv * 64);
#pragma unroll
    for (int c = 0; c < 16; ++c) kr[c] = kp[c];

#pragma unroll
    for (int q = 0; q < 14; ++q) {
        const f4* e = (const f4*)(se + (kh - q + 13) * EPITCH);
        float acc = 0.f;
#pragma unroll
        for (int c = 0; c < 16; ++c) {
            f4 ev = e[c];
            acc += kr[c].x * ev.x + kr[c].y * ev.y + kr[c].z * ev.z + kr[c].w * ev.w;
        }
        relh[(bn * 14 + q) * KLEN + k] = acc;
    }
#pragma unroll
    for (int q = 0; q < 14; ++q) {
        const f4* e = (const f4*)(se + (27 + kw - q + 13) * EPITCH);
        float acc = 0.f;
#pragma unroll
        for (int c = 0; c < 16; ++c) {
            f4 ev = e[c];
            acc += kr[c].x * ev.x + kr[c].y * ev.y + kr[c].z * ev.z + kr[c].w * ev.w;
        }
        relw[(bn * 14 + q) * KLEN + k] = acc;
    }
#pragma unroll
    for (int q = 0; q < 8; ++q) {
        const f4* e = (const f4*)(se + (54 + tk - q + 7) * EPITCH);
        float acc = 0.f;
#pragma unroll
        for (int c = 0; c < 16; ++c) {
            f4 ev = e[c];
            acc += kr[c].x * ev.x + kr[c].y * ev.y + kr[c].z * ev.z + kr[c].w * ev.w;
        }
        relt[(bn * 8 + q) * KLEN + k] = acc;
    }
}

// ---------------- stage 2: broadcast-add with LDS-resident rel tiles -------
// Block = (bn, tq, qh, chunk). Tile = 14 output rows (qw) x 56 f4 columns.
// Staged LDS: rows 0..13 = rel_w[qw], row 14 = rel_h[qh], row 15 = rel_t[tq],
// each 56 f4 (896 B, line-aligned chunks). Inner loop is a pure stream.
#define CH4   56                    // f4 per chunk
#define NCH   7                     // 392 / 56
#define TILE  (14 * CH4)            // 784 f4 of output per block
#define STAGE (16 * CH4)            // 896 f4 staged

__global__ __launch_bounds__(256) void add_staged(const f4* __restrict__ scores,
                                                  const f4* __restrict__ relh,
                                                  const f4* __restrict__ relw,
                                                  const f4* __restrict__ relt,
                                                  f4* __restrict__ out)
{
    __shared__ f4 se[STAGE];

    int b    = blockIdx.x;
    int ch   = b % NCH;   b /= NCH;
    int qh   = b % 14;    b /= 14;
    int tq   = b % 8;
    int bn   = b / 8;

    int tid  = threadIdx.x;
    int cbase = ch * CH4;

    // stage 16 row-chunks of rel into LDS
    for (int e = tid; e < STAGE; e += 256) {
        int row = e / CH4, c = e - row * CH4;
        const f4* src;
        if (row < 14)       src = relw + (size_t)(bn * 14 + row) * KLEN4;
        else if (row == 14) src = relh + (size_t)(bn * 14 + qh) * KLEN4;
        else                src = relt + (size_t)(bn * 8 + tq) * KLEN4;
        se[e] = src[cbase + c];
    }
    __syncthreads();

    const f4* hl = se + 14 * CH4;
    const f4* tl = se + 15 * CH4;

    int qbase = (bn * QLEN + tq * 196 + qh * 14) * KLEN4 + cbase;

    // 784 = 3*256 + 16 : three full passes + tiny tail, loads batched for MLP
    int e0 = tid, e1 = tid + 256, e2 = tid + 512;
    int qw0 = e0 / CH4, c0 = e0 - qw0 * CH4;
    int qw1 = e1 / CH4, c1 = e1 - qw1 * CH4;
    int qw2 = e2 / CH4, c2 = e2 - qw2 * CH4;
    int i0 = qbase + qw0 * KLEN4 + c0;
    int i1 = qbase + qw1 * KLEN4 + c1;
    int i2 = qbase + qw2 * KLEN4 + c2;

    f4 s0 = scores[i0];
    f4 s1 = scores[i1];
    f4 s2 = scores[i2];

    out[i0] = s0 + se[e0] + hl[c0] + tl[c0];
    out[i1] = s1 + se[e1] + hl[c1] + tl[c1];
    out[i2] = s2 + se[e2] + hl[c2] + tl[c2];

    if (tid < TILE - 768) {           // 16 threads
        int e3 = tid + 768;
        int qw3 = e3 / CH4, c3 = e3 - qw3 * CH4;
        int i3 = qbase + qw3 * KLEN4 + c3;
        out[i3] = scores[i3] + se[e3] + hl[c3] + tl[c3];
    }
}

extern "C" void kernel_launch(void* const* d_in, const int* in_sizes, int n_in,
                              void* d_out, int out_size, void* d_ws, size_t ws_size,
                              hipStream_t stream)
{
    const float* key    = (const float*)d_in[0];
    const float* scores = (const float*)d_in[1];
    const float* hemb   = (const float*)d_in[2];
    const float* wemb   = (const float*)d_in[3];
    const float* temb   = (const float*)d_in[4];
    float*       out    = (float*)d_out;

    size_t need = (size_t)(REL_H_ELEMS * 2 + REL_T_ELEMS) * sizeof(float); // ~3.45 MB
    if (ws_size < need) return;

    float* relh = (float*)d_ws;
    float* relw = relh + REL_H_ELEMS;
    float* relt = relw + REL_H_ELEMS;

    rel_fused<<<KV_TOTAL / 128, 128, 0, stream>>>(key, hemb, wemb, temb, relh, relw, relt);

    // grid = bn(16) * tq(8) * qh(14) * chunks(7) = 12544 blocks
    add_staged<<<BN_TOTAL * 8 * 14 * NCH, 256, 0, stream>>>((const f4*)scores,
                                                            (const f4*)relh,
                                                            (const f4*)relw,
                                                            (const f4*)relt,
                                                            (f4*)out);
}

// Round 6
// 74.057 us; speedup vs baseline: 1.2827x; 1.1037x over previous
//
#include <hip/hip_runtime.h>

// Problem constants (fixed by init_kwargs)
//   key:    [B=2, N=8, T_K=8, K_H=14, K_W=14, C=64]  f32
//   scores: [B=2, N=8, 1568, 1568]                   f32
//   h_emb:  [27, 64], w_emb: [27, 64], t_emb: [15, 64]
//   out:    [B, N, 1568, 1568] f32
//
// rel_h[bn, qh, k] = dot(h_emb[kh-qh+13, :], key[bn, k, :])   k = tk*196+kh*14+kw
// rel_w[bn, qw, k] = dot(w_emb[kw-qw+13, :], key[bn, k, :])
// rel_t[bn, tq, k] = dot(t_emb[tk-tq+ 7, :], key[bn, k, :])
// out[bn, (tq,qh,qw), k] = scores + rel_h + rel_w + rel_t

typedef float f4 __attribute__((ext_vector_type(4)));

#define BN_TOTAL    16
#define KLEN        1568
#define KLEN4       392
#define QLEN        1568
#define KV_TOTAL    (BN_TOTAL * KLEN)            // 25088 key vectors
#define REL_H_ELEMS (BN_TOTAL * 14 * KLEN)       // 351232
#define REL_T_ELEMS (BN_TOTAL * 8 * KLEN)        // 200704

#define EROWS  69     // 27 h + 27 w + 15 t
#define EPITCH 68     // 64 + 4 pad floats; 272B row stride (16B aligned)

// ---------------- stage 1: rel tables -------------------------------------
// 4 threads per key vector; each thread owns 9 of the 36 (q, table) dots.
// Branch-free row/dst selection; 392 blocks x 256 threads = 1568 waves.
__global__ __launch_bounds__(256) void rel_fused(const float* __restrict__ key,
                                                 const float* __restrict__ hemb,
                                                 const float* __restrict__ wemb,
                                                 const float* __restrict__ temb,
                                                 float* __restrict__ relh,
                                                 float* __restrict__ relw,
                                                 float* __restrict__ relt)
{
    __shared__ float se[EROWS * EPITCH];
    for (int idx = threadIdx.x; idx < EROWS * 64; idx += 256) {
        int row = idx >> 6, c = idx & 63;
        float v;
        if (row < 27)      v = hemb[row * 64 + c];
        else if (row < 54) v = wemb[(row - 27) * 64 + c];
        else               v = temb[(row - 54) * 64 + c];
        se[row * EPITCH + c] = v;
    }
    __syncthreads();

    int tid  = threadIdx.x;
    int s    = tid & 3;                         // q-slot
    int kv   = blockIdx.x * 64 + (tid >> 2);    // grid exact: 392 blocks
    int bn   = kv / KLEN;
    int k    = kv - bn * KLEN;
    int tk   = k / 196;
    int khw  = k - tk * 196;
    int kh   = khw / 14;
    int kw   = khw - kh * 14;

    f4 kr[16];
    const f4* kp = (const f4*)key + (size_t)kv * 16;
#pragma unroll
    for (int c = 0; c < 16; ++c) kr[c] = kp[c];

#pragma unroll
    for (int j = 0; j < 9; ++j) {
        int qi = s + 4 * j;                     // 0..35
        int row = (qi < 14) ? (kh - qi + 13)
                : (qi < 28) ? (kw - qi + 54)
                            : (tk - qi + 89);
        float* dst = (qi < 14) ? relh + (size_t)(bn * 14 + qi) * KLEN
                   : (qi < 28) ? relw + (size_t)(bn * 14 + qi - 14) * KLEN
                               : relt + (size_t)(bn * 8 + qi - 28) * KLEN;
        const f4* e = (const f4*)(se + row * EPITCH);
        f4 acc4 = {0.f, 0.f, 0.f, 0.f};
#pragma unroll
        for (int c = 0; c < 16; ++c) acc4 += kr[c] * e[c];
        dst[k] = acc4.x + acc4.y + acc4.z + acc4.w;
    }
}

// ---------------- stage 2: broadcast-add, (bn, tq, chunk) tiles ------------
// Block covers all 196 q-rows (qh,qw) of one (bn,tq) for a 28-f4 k-chunk.
// Staged LDS rows: 0..13 = rel_w, 14..27 = rel_h, 28 = rel_t  (29 x 28 f4).
#define CH4    28                   // f4 per chunk (448 B)
#define NCH    14                   // 392 / 28
#define SROWS  29
#define STAGE4 (SROWS * CH4)        // 812 f4 = 12992 B LDS
#define TILE4  (196 * CH4)          // 5488 f4 of output per block

__global__ __launch_bounds__(256) void add_staged(const f4* __restrict__ scores,
                                                  const f4* __restrict__ relh,
                                                  const f4* __restrict__ relw,
                                                  const f4* __restrict__ relt,
                                                  f4* __restrict__ out)
{
    __shared__ f4 se4[STAGE4];

    int tid = threadIdx.x;
    int b   = blockIdx.x;
    int ch  = b % NCH;  b /= NCH;
    int tq  = b & 7;    b >>= 3;
    int bn  = b;
    int cbase = ch * CH4;

    // stage rel rows into LDS (13 KB from L2)
    for (int e = tid; e < STAGE4; e += 256) {
        int r = e / CH4, c = e - r * CH4;
        const f4* src = (r < 14) ? relw + (size_t)(bn * 14 + r) * KLEN4
                      : (r < 28) ? relh + (size_t)(bn * 14 + (r - 14)) * KLEN4
                                 : relt + (size_t)(bn * 8 + tq) * KLEN4;
        se4[e] = src[cbase + c];
    }

    int obase = (bn * QLEN + tq * 196) * KLEN4 + cbase;

#define GIDX(j, e, row, c, gi)                        \
    int e   = tid + (j) * 256;                        \
    int row = e / CH4;                                \
    int c   = e - row * CH4;                          \
    int gi  = obase + row * KLEN4 + c;

#define LOADG(j0, sv, gv)                             \
    {                                                 \
        _Pragma("unroll")                             \
        for (int j = 0; j < 4; ++j) {                 \
            GIDX(j0 + j, e, row, c, gi)               \
            gv[j] = gi;                               \
            sv[j] = scores[gi];                       \
        }                                             \
    }

#define PROCG(j0, sv, gv)                             \
    {                                                 \
        _Pragma("unroll")                             \
        for (int j = 0; j < 4; ++j) {                 \
            GIDX(j0 + j, e, row, c, gi)               \
            int qh = row / 14, qw = row - qh * 14;    \
            f4 v = sv[j] + se4[qw * CH4 + c]          \
                         + se4[(14 + qh) * CH4 + c]   \
                         + se4[28 * CH4 + c];         \
            out[gv[j]] = v;                           \
        }                                             \
    }

    f4 sA[4], sB[4];
    int gA[4], gB[4];

    LOADG(0, sA, gA);
    LOADG(4, sB, gB);
    __syncthreads();          // stage + sA/sB loads all complete here

    PROCG(0, sA, gA);
    LOADG(8, sA, gA);
    PROCG(4, sB, gB);
    LOADG(12, sB, gB);
    PROCG(8, sA, gA);
    LOADG(16, sA, gA);
    PROCG(12, sB, gB);

    // last group: j = 20 full, j = 21 partial (tid < 112)
    {
        f4  sv0, sv1;
        int gi0, gi1;
        bool act1 = (tid < TILE4 - 21 * 256);   // 112 threads
        { GIDX(20, e, row, c, gi) gi0 = gi; sv0 = scores[gi]; }
        if (act1) { GIDX(21, e, row, c, gi) gi1 = gi; sv1 = scores[gi]; }
        PROCG(16, sA, gA);
        {
            GIDX(20, e, row, c, gi)
            int qh = row / 14, qw = row - qh * 14;
            out[gi0] = sv0 + se4[qw * CH4 + c] + se4[(14 + qh) * CH4 + c] + se4[28 * CH4 + c];
        }
        if (act1) {
            GIDX(21, e, row, c, gi)
            int qh = row / 14, qw = row - qh * 14;
            out[gi1] = sv1 + se4[qw * CH4 + c] + se4[(14 + qh) * CH4 + c] + se4[28 * CH4 + c];
        }
    }
#undef GIDX
#undef LOADG
#undef PROCG
}

extern "C" void kernel_launch(void* const* d_in, const int* in_sizes, int n_in,
                              void* d_out, int out_size, void* d_ws, size_t ws_size,
                              hipStream_t stream)
{
    const float* key    = (const float*)d_in[0];
    const float* scores = (const float*)d_in[1];
    const float* hemb   = (const float*)d_in[2];
    const float* wemb   = (const float*)d_in[3];
    const float* temb   = (const float*)d_in[4];
    float*       out    = (float*)d_out;

    size_t need = (size_t)(REL_H_ELEMS * 2 + REL_T_ELEMS) * sizeof(float); // ~3.45 MB
    if (ws_size < need) return;

    float* relh = (float*)d_ws;
    float* relw = relh + REL_H_ELEMS;
    float* relt = relw + REL_H_ELEMS;

    rel_fused<<<KV_TOTAL * 4 / 256, 256, 0, stream>>>(key, hemb, wemb, temb,
                                                      relh, relw, relt);

    // grid = bn(16) * tq(8) * chunks(14) = 1792 blocks = exactly 7 per CU
    add_staged<<<BN_TOTAL * 8 * NCH, 256, 0, stream>>>((const f4*)scores,
                                                       (const f4*)relh,
                                                       (const f4*)relw,
                                                       (const f4*)relt,
                                                       (f4*)out);
}

// Round 7
// 61.594 us; speedup vs baseline: 1.5423x; 1.2023x over previous
//
#include <hip/hip_runtime.h>

// Problem constants (fixed by init_kwargs)
//   key:    [B=2, N=8, T_K=8, K_H=14, K_W=14, C=64]  f32
//   scores: [B=2, N=8, 1568, 1568]                   f32
//   h_emb:  [27, 64], w_emb: [27, 64], t_emb: [15, 64]
//   out:    [B, N, 1568, 1568] f32
//
// rel_h[bn, qh, k] = dot(h_emb[kh-qh+13, :], key[bn, k, :])   k = tk*196+kh*14+kw
// rel_w[bn, qw, k] = dot(w_emb[kw-qw+13, :], key[bn, k, :])
// rel_t[bn, tq, k] = dot(t_emb[tk-tq+ 7, :], key[bn, k, :])
// out[bn, (tq,qh,qw), k] = scores + rel_h + rel_w + rel_t

typedef float f4 __attribute__((ext_vector_type(4)));

#define BN_TOTAL    16
#define KLEN        1568
#define KLEN4       392
#define QLEN        1568
#define KV_TOTAL    (BN_TOTAL * KLEN)            // 25088 key vectors
#define REL_H_ELEMS (BN_TOTAL * 14 * KLEN)       // 351232
#define REL_T_ELEMS (BN_TOTAL * 8 * KLEN)        // 200704

#define EROWS  69     // 27 h + 27 w + 15 t
#define EPITCH 68     // 64 + 4 pad floats; 272B row stride (16B aligned)

// ---------------- stage 1: rel tables (unchanged from R6, ~4 us) ----------
__global__ __launch_bounds__(256) void rel_fused(const float* __restrict__ key,
                                                 const float* __restrict__ hemb,
                                                 const float* __restrict__ wemb,
                                                 const float* __restrict__ temb,
                                                 float* __restrict__ relh,
                                                 float* __restrict__ relw,
                                                 float* __restrict__ relt)
{
    __shared__ float se[EROWS * EPITCH];
    for (int idx = threadIdx.x; idx < EROWS * 64; idx += 256) {
        int row = idx >> 6, c = idx & 63;
        float v;
        if (row < 27)      v = hemb[row * 64 + c];
        else if (row < 54) v = wemb[(row - 27) * 64 + c];
        else               v = temb[(row - 54) * 64 + c];
        se[row * EPITCH + c] = v;
    }
    __syncthreads();

    int tid  = threadIdx.x;
    int s    = tid & 3;                         // q-slot
    int kv   = blockIdx.x * 64 + (tid >> 2);    // grid exact: 392 blocks
    int bn   = kv / KLEN;
    int k    = kv - bn * KLEN;
    int tk   = k / 196;
    int khw  = k - tk * 196;
    int kh   = khw / 14;
    int kw   = khw - kh * 14;

    f4 kr[16];
    const f4* kp = (const f4*)key + (size_t)kv * 16;
#pragma unroll
    for (int c = 0; c < 16; ++c) kr[c] = kp[c];

#pragma unroll
    for (int j = 0; j < 9; ++j) {
        int qi = s + 4 * j;                     // 0..35
        int row = (qi < 14) ? (kh - qi + 13)
                : (qi < 28) ? (kw - qi + 54)
                            : (tk - qi + 89);
        float* dst = (qi < 14) ? relh + (size_t)(bn * 14 + qi) * KLEN
                   : (qi < 28) ? relw + (size_t)(bn * 14 + qi - 14) * KLEN
                               : relt + (size_t)(bn * 8 + qi - 28) * KLEN;
        const f4* e = (const f4*)(se + row * EPITCH);
        f4 acc4 = {0.f, 0.f, 0.f, 0.f};
#pragma unroll
        for (int c = 0; c < 16; ++c) acc4 += kr[c] * e[c];
        dst[k] = acc4.x + acc4.y + acc4.z + acc4.w;
    }
}

// ---------------- stage 2: broadcast-add ----------------------------------
// Block = (bn, tq, qh-half, chunk). Tile = 98 q-rows x 56 f4 columns.
// LDS rows 0..13  = rel_w[qw]          (14 x 56 f4)
//          14..20 = rel_h[qh] + rel_t  ( 7 x 56 f4, t folded in at stage)
// Inner loop: 1 global load + 2 ds_read_b128 + 2 f4 adds + 1 NT store.
#define CH4    56                   // f4 per chunk (896 B segments)
#define NCH    7                    // 392 / 56
#define SROWS  21                   // 14 w + 7 ht
#define STAGE4 (SROWS * CH4)        // 1176 f4 = 18816 B LDS
#define TILE4  (98 * CH4)           // 5488 f4 per block = 21*256 + 112

__global__ __launch_bounds__(256) void add_staged(const f4* __restrict__ scores,
                                                  const f4* __restrict__ relh,
                                                  const f4* __restrict__ relw,
                                                  const f4* __restrict__ relt,
                                                  f4* __restrict__ out)
{
    __shared__ f4 se[STAGE4];

    int tid = threadIdx.x;
    int b   = blockIdx.x;
    int ch  = b % NCH;  b /= NCH;
    int half = b & 1;   b >>= 1;
    int tq  = b & 7;    b >>= 3;
    int bn  = b;
    int cbase = ch * CH4;

    const f4* wrow = relw + (size_t)(bn * 14) * KLEN4 + cbase;
    const f4* hrow = relh + (size_t)(bn * 14 + half * 7) * KLEN4 + cbase;
    const f4* trow = relt + (size_t)(bn * 8 + tq) * KLEN4 + cbase;

    // stage rel into LDS; fold t into the h rows
    for (int e = tid; e < STAGE4; e += 256) {
        int r = e / CH4, c = e - r * CH4;
        f4 v;
        if (r < 14) v = wrow[(size_t)r * KLEN4 + c];
        else        v = hrow[(size_t)(r - 14) * KLEN4 + c] + trow[c];
        se[e] = v;
    }

    int obase = (bn * QLEN + tq * 196 + half * 98) * KLEN4 + cbase;

#define EIDX(J, e, row, c, gi)                        \
    int e   = tid + (J) * 256;                        \
    int row = e / CH4;                                \
    int c   = e - row * CH4;                          \
    int gi  = obase + row * KLEN4 + c;

#define LOAD3(G, sv)                                  \
    {                                                 \
        _Pragma("unroll")                             \
        for (int jj = 0; jj < 3; ++jj) {              \
            EIDX(3 * (G) + jj, e, row, c, gi)         \
            sv[jj] = scores[gi];                      \
        }                                             \
    }

#define PROC3(G, sv)                                  \
    {                                                 \
        _Pragma("unroll")                             \
        for (int jj = 0; jj < 3; ++jj) {              \
            EIDX(3 * (G) + jj, e, row, c, gi)         \
            int qhl = row / 14, qw = row - qhl * 14;  \
            f4 v = sv[jj] + se[qw * CH4 + c]          \
                          + se[(14 + qhl) * CH4 + c]; \
            __builtin_nontemporal_store(v, out + gi); \
        }                                             \
    }

    f4 sA[3], sB[3];

    LOAD3(0, sA);
    LOAD3(1, sB);
    __syncthreads();            // stage complete (also drains sA/sB loads)

    PROC3(0, sA);  LOAD3(2, sA);
    PROC3(1, sB);  LOAD3(3, sB);
    PROC3(2, sA);  LOAD3(4, sA);
    PROC3(3, sB);  LOAD3(5, sB);
    PROC3(4, sA);  LOAD3(6, sA);
    PROC3(5, sB);
    PROC3(6, sA);

    // tail: 112 threads, one f4 each (group index 21)
    if (tid < TILE4 - 21 * 256) {
        EIDX(21, e, row, c, gi)
        int qhl = row / 14, qw = row - qhl * 14;
        f4 v = scores[gi] + se[qw * CH4 + c] + se[(14 + qhl) * CH4 + c];
        __builtin_nontemporal_store(v, out + gi);
    }
#undef EIDX
#undef LOAD3
#undef PROC3
}

extern "C" void kernel_launch(void* const* d_in, const int* in_sizes, int n_in,
                              void* d_out, int out_size, void* d_ws, size_t ws_size,
                              hipStream_t stream)
{
    const float* key    = (const float*)d_in[0];
    const float* scores = (const float*)d_in[1];
    const float* hemb   = (const float*)d_in[2];
    const float* wemb   = (const float*)d_in[3];
    const float* temb   = (const float*)d_in[4];
    float*       out    = (float*)d_out;

    size_t need = (size_t)(REL_H_ELEMS * 2 + REL_T_ELEMS) * sizeof(float); // ~3.45 MB
    if (ws_size < need) return;

    float* relh = (float*)d_ws;
    float* relw = relh + REL_H_ELEMS;
    float* relt = relw + REL_H_ELEMS;

    rel_fused<<<KV_TOTAL * 4 / 256, 256, 0, stream>>>(key, hemb, wemb, temb,
                                                      relh, relw, relt);

    // grid = bn(16) * tq(8) * half(2) * chunks(7) = 1792 = 7 blocks/CU exact
    add_staged<<<BN_TOTAL * 8 * 2 * NCH, 256, 0, stream>>>((const f4*)scores,
                                                           (const f4*)relh,
                                                           (const f4*)relw,
                                                           (const f4*)relt,
                                                           (f4*)out);
}